// Round 10
// baseline (311.819 us; speedup 1.0000x reference)
//
#include <hip/hip_runtime.h>
#include <hip/hip_bf16.h>

#define BATCH 4
#define CH    512
#define NPIX  4096
#define LOG2E 1.4426950408889634f

#define BOFF  327680
#define WTOT  328320
#define PSTR  268         // P row stride (u16): b64-aligned, 2-way banks max

typedef float v4f __attribute__((ext_vector_type(4)));
typedef short v8s __attribute__((ext_vector_type(8)));
typedef unsigned short u16;

__device__ __forceinline__ float b2f(u16 v){
    union { unsigned u; float f; } x; x.u = ((unsigned)v) << 16; return x.f;
}
__device__ __forceinline__ u16 f2b(float f){
    union { float f; unsigned u; } x; x.f = f;
    unsigned r = x.u + 0x7fffu + ((x.u >> 16) & 1u);
    return (u16)(r >> 16);
}
__device__ __forceinline__ void f2b2(float a, float b, u16* o){
    union { __hip_bfloat162 v; u16 s[2]; } u;
    u.v = __float22bfloat162_rn(make_float2(a, b));
    o[0] = u.s[0]; o[1] = u.s[1];
}
__device__ __forceinline__ float fexp2(float x){
#if __has_builtin(__builtin_amdgcn_exp2f)
    return __builtin_amdgcn_exp2f(x);
#else
    return exp2f(x);
#endif
}
__device__ __forceinline__ v4f mfma16(v8s a, v8s b, v4f c){
    return __builtin_amdgcn_mfma_f32_16x16x32_bf16(a, b, c, 0, 0, 0);
}
__device__ __forceinline__ float load_s(const void* p, size_t idx, int isf32){
    return isf32 ? ((const float*)p)[idx] : b2f(((const u16*)p)[idx]);
}

// ---------------------------------------------------------------------------
__global__ void detect_kernel(const unsigned* __restrict__ x, int* __restrict__ flag){
    __shared__ int cnt;
    if (threadIdx.x == 0) cnt = 0;
    __syncthreads();
    int c = 0;
    for (int i = threadIdx.x; i < 1024; i += 64){
        unsigned e = (x[i] >> 23) & 0xFFu;
        if (e >= 64u && e < 192u) c++;
    }
    atomicAdd(&cnt, c);
    __syncthreads();
    if (threadIdx.x == 0) flag[0] = (cnt > 512) ? 1 : 0;
}

// ---------------------------------------------------------------------------
__global__ __launch_bounds__(256) void prep_kernel(
    const void* __restrict__ wq, const void* __restrict__ bq,
    const void* __restrict__ wk, const void* __restrict__ bk,
    const void* __restrict__ wv, const void* __restrict__ bv,
    u16* __restrict__ wall, const int* __restrict__ flag)
{
    const int isf32 = flag[0];
    int i = blockIdx.x * 256 + threadIdx.x;
    if (i >= WTOT) return;
    float v;
    if (i < BOFF){
        int o = i >> 9, c = i & 511;
        if (o < 64)       v = load_s(wq, (size_t)o * 512 + c, isf32);
        else if (o < 128) v = load_s(wk, (size_t)(o - 64) * 512 + c, isf32);
        else              v = load_s(wv, (size_t)(o - 128) * 512 + c, isf32);
    } else {
        int o = i - BOFF;
        if (o < 64)       v = load_s(bq, o, isf32);
        else if (o < 128) v = load_s(bk, o - 64, isf32);
        else              v = load_s(bv, o - 128, isf32);
    }
    wall[i] = f2b(v);
}

// ---------------------------------------------------------------------------
// Projection (R8 version, reverted): 64-n blocks, BK=32, 16 iters,
// register-prefetched x staging, fragment-order outputs, writes xbf.
// Grid (64 ntile, 4 b), 512 thr = 8 waves; wave w owns out-rows 80w..80w+79.
// ---------------------------------------------------------------------------
__global__ __launch_bounds__(512, 2) void proj_kernel(
    const void* __restrict__ x, const u16* __restrict__ wall,
    u16* __restrict__ Qf, u16* __restrict__ Kf, u16* __restrict__ Vf,
    u16* __restrict__ xbf, const int* __restrict__ flag)
{
    const int isf32 = flag[0];
    const int ntile = blockIdx.x, b = blockIdx.y;
    const int n0 = ntile * 64;
    const int t = threadIdx.x, lane = t & 63, w = t >> 6, q = lane >> 4, col = lane & 15;

    __shared__ __align__(16) u16 xT[2][64 * 40];

    const int rrow  = t >> 4;        // 0..31 : c within chunk
    const int ncol4 = (t & 15) * 4;  // 4 n per thread
    const size_t xbase = (size_t)b * CH * NPIX + n0 + ncol4;

    v4f acc[5][4];
    #pragma unroll
    for (int i = 0; i < 5; i++)
        #pragma unroll
        for (int j = 0; j < 4; j++) acc[i][j] = (v4f){0.f, 0.f, 0.f, 0.f};

    #define LOADX(dst_f4, cb_) do {                                          \
        const size_t src = xbase + (size_t)((cb_) * 32 + rrow) * NPIX;       \
        if (isf32) dst_f4 = *(const float4*)((const float*)x + src);         \
        else {                                                               \
            union { uint2 v; float2 f; } ldu;                                \
            ldu.v = *(const uint2*)((const u16*)x + src);                    \
            dst_f4.x = ldu.f.x; dst_f4.y = ldu.f.y; dst_f4.z = 0; dst_f4.w = 0; \
        }                                                                    \
    } while (0)

    #define CVT4(vals_, f4_) do {                                            \
        if (isf32){ f2b2(f4_.x, f4_.y, &vals_[0]); f2b2(f4_.z, f4_.w, &vals_[2]); } \
        else { union { float2 f; uint2 v; } uu; uu.f = make_float2(f4_.x, f4_.y);   \
               union { uint2 v; u16 s[4]; } ss; ss.v = uu.v;                 \
               vals_[0]=ss.s[0]; vals_[1]=ss.s[1]; vals_[2]=ss.s[2]; vals_[3]=ss.s[3]; } \
    } while (0)

    float4 g_next;
    {
        float4 g0; LOADX(g0, 0);
        u16 vals[4]; CVT4(vals, g0);
        #pragma unroll
        for (int i = 0; i < 4; i++) xT[0][(ncol4 + i) * 40 + rrow] = vals[i];
        *(uint2*)&xbf[(size_t)(b * CH + rrow) * NPIX + n0 + ncol4] = *(uint2*)vals;
        LOADX(g_next, 1);
    }
    __syncthreads();

    for (int cb = 0; cb < 16; cb++){
        const int buf = cb & 1;
        const int c0 = cb * 32 + q * 8;

        v8s wf[5];
        #pragma unroll
        for (int ct = 0; ct < 5; ct++)
            wf[ct] = *(const v8s*)&wall[(size_t)(80 * w + 16 * ct + col) * 512 + c0];

        v8s a[4];
        #pragma unroll
        for (int g = 0; g < 4; g++)
            a[g] = *(const v8s*)&xT[buf][(16 * g + col) * 40 + q * 8];

        if (cb < 15){
            u16 vals[4]; CVT4(vals, g_next);
            #pragma unroll
            for (int i = 0; i < 4; i++) xT[buf ^ 1][(ncol4 + i) * 40 + rrow] = vals[i];
            *(uint2*)&xbf[(size_t)(b * CH + (cb + 1) * 32 + rrow) * NPIX + n0 + ncol4] = *(uint2*)vals;
            if (cb < 14) LOADX(g_next, cb + 2);
        }

        #pragma unroll
        for (int ct = 0; ct < 5; ct++)
            #pragma unroll
            for (int g = 0; g < 4; g++)
                acc[ct][g] = mfma16(a[g], wf[ct], acc[ct][g]);
        __syncthreads();
    }
    #undef LOADX
    #undef CVT4

    const u16* ball = wall + BOFF;
    #pragma unroll
    for (int ct = 0; ct < 5; ct++){
        const int o = 80 * w + 16 * ct + col;
        const float bv_ = b2f(ball[o]);
        #pragma unroll
        for (int g = 0; g < 4; g++){
            const int nb = n0 + 16 * g + 4 * q;
            if (o < 64){
                const int k = o;
                size_t base = (size_t)b * NPIX * 64
                    + ((size_t)((nb >> 4) * 2 + (k >> 5))) * 512
                    + ((k & 31) >> 3) * 128 + (nb & 15) * 8 + (k & 7);
                #pragma unroll
                for (int r = 0; r < 4; r++)
                    Qf[base + r * 8] = f2b((acc[ct][g][r] + bv_) * LOG2E);
            } else if (o < 128){
                const int k = o - 64;
                size_t base = (size_t)b * NPIX * 64
                    + ((size_t)((nb >> 4) * 2 + (k >> 5))) * 512
                    + ((k & 31) >> 3) * 128 + (nb & 15) * 8 + (k & 7);
                #pragma unroll
                for (int r = 0; r < 4; r++)
                    Kf[base + r * 8] = f2b(acc[ct][g][r] + bv_);
            } else {
                const int c = o - 128;
                size_t base = (size_t)b * CH * NPIX
                    + ((size_t)((c >> 4) * 128 + (nb >> 5))) * 512
                    + ((nb & 31) >> 3) * 128 + (c & 15) * 8 + (nb & 7);
                union { uint2 u; u16 s[4]; } ov;
                #pragma unroll
                for (int r = 0; r < 4; r++)
                    ov.s[r] = f2b(acc[ct][g][r] + bv_);
                *(uint2*)&Vf[base] = ov.u;
            }
        }
    }
}

// ---------------------------------------------------------------------------
// Flash attention v10 (R9 + deep prefetch, same occupancy bin):
// - kf cross-iteration double-buffer: kf(it+1) issued right after barrier(it),
//   hidden under PV(it); it-loop unrolled x2 so buffer parity is constant.
// - va 2-deep rotation in PV (loads ~250 cyc ahead of use).
// Br=128, Bc=256, c-split x2, 8 waves, grid 256, 1 barrier/iter, P dbuf.
// ---------------------------------------------------------------------------
__global__ __launch_bounds__(512, 2) void attn_kernel(
    const u16* __restrict__ Qf, const u16* __restrict__ Kf, const u16* __restrict__ Vf,
    const u16* __restrict__ xbf, const void* __restrict__ gamma,
    void* __restrict__ out, const int* __restrict__ flag)
{
    const int isf32 = flag[0];
    const int bid = blockIdx.x;
    const int csplit = bid & 1;
    const int b      = (bid >> 1) & 3;
    const int ntile  = bid >> 3;
    const int n0 = ntile * 128;

    const int t = threadIdx.x, lane = t & 63, w = t >> 6, q = lane >> 4, col = lane & 15;
    const int nh = w & 1;
    const int ws = w >> 1;

    __shared__ __align__(16) u16  Plds[2][128 * PSTR];
    __shared__ __align__(16) float lsum[8][64];

    const u16* Qb = Qf + (size_t)b * NPIX * 64;
    const u16* Kb = Kf + (size_t)b * NPIX * 64;
    const u16* Vb = Vf + (size_t)b * CH * NPIX;

    v8s qa[4][2];
    #pragma unroll
    for (int g = 0; g < 4; g++)
        #pragma unroll
        for (int c2 = 0; c2 < 2; c2++)
            qa[g][c2] = *(const v8s*)&Qb[(size_t)((((n0 + 64 * nh) >> 4) + g) * 2 + c2) * 512 + lane * 8];

    float lreg[4] = {0.f, 0.f, 0.f, 0.f};

    v4f oacc[4][4];
    #pragma unroll
    for (int i = 0; i < 4; i++)
        #pragma unroll
        for (int j = 0; j < 4; j++) oacc[i][j] = (v4f){0.f, 0.f, 0.f, 0.f};

    const int ms    = 64 * ws;
    const int cslab = csplit * 256 + 64 * ws;

    // kf double-buffer across iterations: prologue loads it=0 into kfb[0]
    v8s kfb[2][4][2];
    #pragma unroll
    for (int mt = 0; mt < 4; mt++)
        #pragma unroll
        for (int c2 = 0; c2 < 2; c2++)
            kfb[0][mt][c2] = *(const v8s*)&Kb[(size_t)(((ms >> 4) + mt) * 2 + c2) * 512 + lane * 8];

    #pragma unroll 2
    for (int it = 0; it < 16; it++){
        const int m0 = it * 256;
        const int buf = it & 1;

        // ---- S^T = K Q^T - 64 (rows=m, cols=n); P -> LDS (packed b64) ----
        #pragma unroll
        for (int g = 0; g < 4; g++){
            #pragma unroll
            for (int mt = 0; mt < 4; mt++){
                v4f sv = (v4f){-64.f, -64.f, -64.f, -64.f};
                sv = mfma16(kfb[buf][mt][0], qa[g][0], sv);
                sv = mfma16(kfb[buf][mt][1], qa[g][1], sv);
                float p0 = fexp2(sv[0]), p1 = fexp2(sv[1]);
                float p2 = fexp2(sv[2]), p3 = fexp2(sv[3]);
                lreg[g] += (p0 + p1) + (p2 + p3);
                union { uint2 u; u16 s[4]; } pk;
                f2b2(p0, p1, &pk.s[0]);
                f2b2(p2, p3, &pk.s[2]);
                *(uint2*)&Plds[buf][(64 * nh + 16 * g + col) * PSTR + ms + 16 * mt + 4 * q] = pk.u;
            }
        }

        __syncthreads();   // P[buf] complete; P[buf^1] consumed last iter

        // ---- issue kf loads for it+1 (land under PV's MFMA stream) ----
        if (it < 15){
            const int m1 = (it + 1) * 256;
            #pragma unroll
            for (int mt = 0; mt < 4; mt++)
                #pragma unroll
                for (int c2 = 0; c2 < 2; c2++)
                    kfb[buf ^ 1][mt][c2] = *(const v8s*)&Kb[(size_t)((((m1 + ms) >> 4) + mt) * 2 + c2) * 512 + lane * 8];
        }

        // ---- PV: O[c][n] += V[c][m] P[n][m]; va 2-deep rotation ----
        v8s vab[2][4];
        #pragma unroll
        for (int ct = 0; ct < 4; ct++){
            vab[0][ct] = *(const v8s*)&Vb[(size_t)(((cslab + 16 * ct) >> 4) * 128 + (m0 >> 5) + 0) * 512 + lane * 8];
            vab[1][ct] = *(const v8s*)&Vb[(size_t)(((cslab + 16 * ct) >> 4) * 128 + (m0 >> 5) + 1) * 512 + lane * 8];
        }
        #pragma unroll
        for (int kk = 0; kk < 8; kk++){
            const int cur = kk & 1;
            v8s pb[4];
            #pragma unroll
            for (int nt = 0; nt < 4; nt++)
                pb[nt] = *(const v8s*)&Plds[buf][(64 * nh + 16 * nt + col) * PSTR + 32 * kk + q * 8];
            #pragma unroll
            for (int ct = 0; ct < 4; ct++)
                #pragma unroll
                for (int nt = 0; nt < 4; nt++)
                    oacc[ct][nt] = mfma16(vab[cur][ct], pb[nt], oacc[ct][nt]);
            if (kk < 6){
                #pragma unroll
                for (int ct = 0; ct < 4; ct++)
                    vab[cur][ct] = *(const v8s*)&Vb[(size_t)(((cslab + 16 * ct) >> 4) * 128 + (m0 >> 5) + kk + 2) * 512 + lane * 8];
            }
        }
    }

    // ---- finalize l ----
    #pragma unroll
    for (int g = 0; g < 4; g++){
        lreg[g] += __shfl_xor(lreg[g], 16);
        lreg[g] += __shfl_xor(lreg[g], 32);
    }
    if (lane < 16){
        #pragma unroll
        for (int g = 0; g < 4; g++)
            lsum[w][16 * g + lane] = lreg[g];
    }
    __syncthreads();

    const float gam = load_s(gamma, 0, isf32);
    float linv[4];
    #pragma unroll
    for (int nt = 0; nt < 4; nt++){
        int nn = 16 * nt + col;
        float l = lsum[nh][nn] + lsum[2 + nh][nn] + lsum[4 + nh][nn] + lsum[6 + nh][nn];
        linv[nt] = gam / l;
    }

    // ---- epilogue: out = gamma*O/l + xbf ----
    const size_t boff = (size_t)b * CH * NPIX;
    #pragma unroll
    for (int ct = 0; ct < 4; ct++){
        #pragma unroll
        for (int rr = 0; rr < 4; rr++){
            int c = cslab + 16 * ct + 4 * q + rr;
            size_t base = boff + (size_t)c * NPIX + n0 + 64 * nh;
            #pragma unroll
            for (int nt = 0; nt < 4; nt++){
                int n = 16 * nt + col;
                float o = oacc[ct][nt][rr] * linv[nt] + b2f(xbf[base + n]);
                if (isf32) ((float*)out)[base + n] = o;
                else       ((u16*)out)[base + n]  = f2b(o);
            }
        }
    }
}

// ---------------------------------------------------------------------------
extern "C" void kernel_launch(void* const* d_in, const int* in_sizes, int n_in,
                              void* d_out, int out_size, void* d_ws, size_t ws_size,
                              hipStream_t stream)
{
    const void* x     = d_in[0];
    const void* wq    = d_in[1];
    const void* bq    = d_in[2];
    const void* wk    = d_in[3];
    const void* bk    = d_in[4];
    const void* wv    = d_in[5];
    const void* bv    = d_in[6];
    const void* gamma = d_in[7];

    u16* Qf   = (u16*)d_ws;                   // [B][N/16][2][512]
    u16* Kf   = Qf + (size_t)1048576;
    u16* Vf   = Kf + (size_t)1048576;         // [B][C/16][128][512]
    u16* xbf  = Vf + (size_t)8388608;         // [B][C][N] bf16
    u16* wall = xbf + (size_t)8388608;
    int* flag = (int*)(wall + WTOT + 16);

    detect_kernel<<<1, 64, 0, stream>>>((const unsigned*)x, flag);
    prep_kernel<<<(WTOT + 255) / 256, 256, 0, stream>>>(wq, bq, wk, bk, wv, bv, wall, flag);
    proj_kernel<<<dim3(64, BATCH), 512, 0, stream>>>(x, wall, Qf, Kf, Vf, xbf, flag);
    attn_kernel<<<256, 512, 0, stream>>>(Qf, Kf, Vf, xbf, gamma, d_out, flag);
}

// Round 11
// 233.551 us; speedup vs baseline: 1.3351x; 1.3351x over previous
//
#include <hip/hip_runtime.h>
#include <hip/hip_bf16.h>

#define BATCH 4
#define CH    512
#define NPIX  4096
#define LOG2E 1.4426950408889634f

#define BOFF  327680
#define WTOT  328320
#define PSTR  268         // P row stride (u16): b64-aligned, 2-way banks max

typedef float v4f __attribute__((ext_vector_type(4)));
typedef short v8s __attribute__((ext_vector_type(8)));
typedef unsigned short u16;

__device__ __forceinline__ float b2f(u16 v){
    union { unsigned u; float f; } x; x.u = ((unsigned)v) << 16; return x.f;
}
__device__ __forceinline__ u16 f2b(float f){
    union { float f; unsigned u; } x; x.f = f;
    unsigned r = x.u + 0x7fffu + ((x.u >> 16) & 1u);
    return (u16)(r >> 16);
}
__device__ __forceinline__ void f2b2(float a, float b, u16* o){
    union { __hip_bfloat162 v; u16 s[2]; } u;
    u.v = __float22bfloat162_rn(make_float2(a, b));
    o[0] = u.s[0]; o[1] = u.s[1];
}
__device__ __forceinline__ float fexp2(float x){
#if __has_builtin(__builtin_amdgcn_exp2f)
    return __builtin_amdgcn_exp2f(x);
#else
    return exp2f(x);
#endif
}
__device__ __forceinline__ v4f mfma16(v8s a, v8s b, v4f c){
    return __builtin_amdgcn_mfma_f32_16x16x32_bf16(a, b, c, 0, 0, 0);
}
__device__ __forceinline__ float load_s(const void* p, size_t idx, int isf32){
    return isf32 ? ((const float*)p)[idx] : b2f(((const u16*)p)[idx]);
}

// ---------------------------------------------------------------------------
__global__ void detect_kernel(const unsigned* __restrict__ x, int* __restrict__ flag){
    __shared__ int cnt;
    if (threadIdx.x == 0) cnt = 0;
    __syncthreads();
    int c = 0;
    for (int i = threadIdx.x; i < 1024; i += 64){
        unsigned e = (x[i] >> 23) & 0xFFu;
        if (e >= 64u && e < 192u) c++;
    }
    atomicAdd(&cnt, c);
    __syncthreads();
    if (threadIdx.x == 0) flag[0] = (cnt > 512) ? 1 : 0;
}

// ---------------------------------------------------------------------------
__global__ __launch_bounds__(256) void prep_kernel(
    const void* __restrict__ wq, const void* __restrict__ bq,
    const void* __restrict__ wk, const void* __restrict__ bk,
    const void* __restrict__ wv, const void* __restrict__ bv,
    u16* __restrict__ wall, const int* __restrict__ flag)
{
    const int isf32 = flag[0];
    int i = blockIdx.x * 256 + threadIdx.x;
    if (i >= WTOT) return;
    float v;
    if (i < BOFF){
        int o = i >> 9, c = i & 511;
        if (o < 64)       v = load_s(wq, (size_t)o * 512 + c, isf32);
        else if (o < 128) v = load_s(wk, (size_t)(o - 64) * 512 + c, isf32);
        else              v = load_s(wv, (size_t)(o - 128) * 512 + c, isf32);
    } else {
        int o = i - BOFF;
        if (o < 64)       v = load_s(bq, o, isf32);
        else if (o < 128) v = load_s(bk, o - 64, isf32);
        else              v = load_s(bv, o - 128, isf32);
    }
    wall[i] = f2b(v);
}

// ---------------------------------------------------------------------------
// Projection v11: 256-thr blocks (4 waves), output rows split x2 (os),
// grid (64 ntile, 2 os, 4 b) = 512 blocks -> 2 blocks/CU with INDEPENDENT
// barriers (cross-block latency hiding at fixed waves/SIMD).
// Wave-level structure = R8: wave owns 80 rows (5 ct), 4 n-groups, BK=32,
// register-prefetched x, fragment-order outputs. xbf written by os==0 only.
// ---------------------------------------------------------------------------
__global__ __launch_bounds__(256, 2) void proj_kernel(
    const void* __restrict__ x, const u16* __restrict__ wall,
    u16* __restrict__ Qf, u16* __restrict__ Kf, u16* __restrict__ Vf,
    u16* __restrict__ xbf, const int* __restrict__ flag)
{
    const int isf32 = flag[0];
    const int ntile = blockIdx.x, os = blockIdx.y, b = blockIdx.z;
    const int n0 = ntile * 64;
    const int t = threadIdx.x, lane = t & 63, w = t >> 6, q = lane >> 4, col = lane & 15;

    __shared__ __align__(16) u16 xT[2][64 * 40];

    const int rrow  = t >> 3;        // 0..31 : c within chunk
    const int ncol8 = (t & 7) * 8;   // 8 n per thread
    const size_t xbase = (size_t)b * CH * NPIX + n0 + ncol8;

    v4f acc[5][4];
    #pragma unroll
    for (int i = 0; i < 5; i++)
        #pragma unroll
        for (int j = 0; j < 4; j++) acc[i][j] = (v4f){0.f, 0.f, 0.f, 0.f};

    float4 gn0, gn1;   // prefetch regs (fp32: 8 floats; bf16: uint4 in gn0)

    #define LOADX(cb_) do {                                                  \
        const size_t src = xbase + (size_t)((cb_) * 32 + rrow) * NPIX;       \
        if (isf32){ gn0 = *(const float4*)((const float*)x + src);           \
                    gn1 = *(const float4*)((const float*)x + src + 4); }     \
        else { union { uint4 v; float4 f; } lu;                              \
               lu.v = *(const uint4*)((const u16*)x + src); gn0 = lu.f; }    \
    } while (0)

    #define CVT8(vals_) do {                                                 \
        if (isf32){ f2b2(gn0.x, gn0.y, &vals_[0]); f2b2(gn0.z, gn0.w, &vals_[2]); \
                    f2b2(gn1.x, gn1.y, &vals_[4]); f2b2(gn1.z, gn1.w, &vals_[6]); } \
        else { union { float4 f; uint4 v; } uu; uu.f = gn0;                  \
               *(uint4*)vals_ = uu.v; }                                      \
    } while (0)

    {
        LOADX(0);
        u16 vals[8]; CVT8(vals);
        #pragma unroll
        for (int i = 0; i < 8; i++) xT[0][(ncol8 + i) * 40 + rrow] = vals[i];
        if (os == 0)
            *(uint4*)&xbf[(size_t)(b * CH + rrow) * NPIX + n0 + ncol8] = *(uint4*)vals;
        LOADX(1);
    }
    __syncthreads();

    for (int cb = 0; cb < 16; cb++){
        const int buf = cb & 1;
        const int c0 = cb * 32 + q * 8;

        v8s wf[5];
        #pragma unroll
        for (int ct = 0; ct < 5; ct++)
            wf[ct] = *(const v8s*)&wall[(size_t)(320 * os + 80 * w + 16 * ct + col) * 512 + c0];

        v8s a[4];
        #pragma unroll
        for (int g = 0; g < 4; g++)
            a[g] = *(const v8s*)&xT[buf][(16 * g + col) * 40 + q * 8];

        if (cb < 15){
            u16 vals[8]; CVT8(vals);
            #pragma unroll
            for (int i = 0; i < 8; i++) xT[buf ^ 1][(ncol8 + i) * 40 + rrow] = vals[i];
            if (os == 0)
                *(uint4*)&xbf[(size_t)(b * CH + (cb + 1) * 32 + rrow) * NPIX + n0 + ncol8] = *(uint4*)vals;
            if (cb < 14) LOADX(cb + 2);
        }

        #pragma unroll
        for (int ct = 0; ct < 5; ct++)
            #pragma unroll
            for (int g = 0; g < 4; g++)
                acc[ct][g] = mfma16(a[g], wf[ct], acc[ct][g]);
        __syncthreads();
    }
    #undef LOADX
    #undef CVT8

    // ---- epilogue: fragment-order writes ----
    const u16* ball = wall + BOFF;
    #pragma unroll
    for (int ct = 0; ct < 5; ct++){
        const int o = 320 * os + 80 * w + 16 * ct + col;
        const float bv_ = b2f(ball[o]);
        #pragma unroll
        for (int g = 0; g < 4; g++){
            const int nb = n0 + 16 * g + 4 * q;
            if (o < 64){
                const int k = o;
                size_t base = (size_t)b * NPIX * 64
                    + ((size_t)((nb >> 4) * 2 + (k >> 5))) * 512
                    + ((k & 31) >> 3) * 128 + (nb & 15) * 8 + (k & 7);
                #pragma unroll
                for (int r = 0; r < 4; r++)
                    Qf[base + r * 8] = f2b((acc[ct][g][r] + bv_) * LOG2E);
            } else if (o < 128){
                const int k = o - 64;
                size_t base = (size_t)b * NPIX * 64
                    + ((size_t)((nb >> 4) * 2 + (k >> 5))) * 512
                    + ((k & 31) >> 3) * 128 + (nb & 15) * 8 + (k & 7);
                #pragma unroll
                for (int r = 0; r < 4; r++)
                    Kf[base + r * 8] = f2b(acc[ct][g][r] + bv_);
            } else {
                const int c = o - 128;
                size_t base = (size_t)b * CH * NPIX
                    + ((size_t)((c >> 4) * 128 + (nb >> 5))) * 512
                    + ((nb & 31) >> 3) * 128 + (c & 15) * 8 + (nb & 7);
                union { uint2 u; u16 s[4]; } ov;
                #pragma unroll
                for (int r = 0; r < 4; r++)
                    ov.s[r] = f2b(acc[ct][g][r] + bv_);
                *(uint2*)&Vf[base] = ov.u;
            }
        }
    }
}

// ---------------------------------------------------------------------------
// Flash attention v11: Br=64, Bc=256, c-split x2, 4-wave blocks (256 thr),
// grid 512 -> 2 blocks/CU with independent barriers. Per-wave structure = R9
// (operand-swapped S, packed b64 P writes, raw exp2, 1 barrier/iter, P dbuf).
// Wave w: S m-strip 64w; PV c-slab csplit*256+64w; all 64 n.
// ---------------------------------------------------------------------------
__global__ __launch_bounds__(256, 2) void attn_kernel(
    const u16* __restrict__ Qf, const u16* __restrict__ Kf, const u16* __restrict__ Vf,
    const u16* __restrict__ xbf, const void* __restrict__ gamma,
    void* __restrict__ out, const int* __restrict__ flag)
{
    const int isf32 = flag[0];
    const int bid = blockIdx.x;
    const int csplit = bid & 1;
    const int b      = (bid >> 1) & 3;
    const int ntile  = bid >> 3;          // 0..63
    const int n0 = ntile * 64;

    const int t = threadIdx.x, lane = t & 63, w = t >> 6, q = lane >> 4, col = lane & 15;

    __shared__ __align__(16) u16  Plds[2][64 * PSTR];
    __shared__ __align__(16) float lsum[4][64];

    const u16* Qb = Qf + (size_t)b * NPIX * 64;
    const u16* Kb = Kf + (size_t)b * NPIX * 64;
    const u16* Vb = Vf + (size_t)b * CH * NPIX;

    v8s qa[4][2];
    #pragma unroll
    for (int g = 0; g < 4; g++)
        #pragma unroll
        for (int c2 = 0; c2 < 2; c2++)
            qa[g][c2] = *(const v8s*)&Qb[(size_t)(((n0 >> 4) + g) * 2 + c2) * 512 + lane * 8];

    float lreg[4] = {0.f, 0.f, 0.f, 0.f};

    v4f oacc[4][4];
    #pragma unroll
    for (int i = 0; i < 4; i++)
        #pragma unroll
        for (int j = 0; j < 4; j++) oacc[i][j] = (v4f){0.f, 0.f, 0.f, 0.f};

    const int ms    = 64 * w;
    const int cslab = csplit * 256 + 64 * w;

    for (int it = 0; it < 16; it++){
        const int m0 = it * 256;
        const int buf = it & 1;

        // ---- K-frags for this wave's exclusive 64-m strip ----
        v8s kf[4][2];
        #pragma unroll
        for (int mt = 0; mt < 4; mt++)
            #pragma unroll
            for (int c2 = 0; c2 < 2; c2++)
                kf[mt][c2] = *(const v8s*)&Kb[(size_t)((((m0 + ms) >> 4) + mt) * 2 + c2) * 512 + lane * 8];

        // ---- S^T = K Q^T - 64 (rows=m, cols=n); P -> LDS packed b64 ----
        #pragma unroll
        for (int g = 0; g < 4; g++){
            #pragma unroll
            for (int mt = 0; mt < 4; mt++){
                v4f sv = (v4f){-64.f, -64.f, -64.f, -64.f};
                sv = mfma16(kf[mt][0], qa[g][0], sv);
                sv = mfma16(kf[mt][1], qa[g][1], sv);
                float p0 = fexp2(sv[0]), p1 = fexp2(sv[1]);
                float p2 = fexp2(sv[2]), p3 = fexp2(sv[3]);
                lreg[g] += (p0 + p1) + (p2 + p3);
                union { uint2 u; u16 s[4]; } pk;
                f2b2(p0, p1, &pk.s[0]);
                f2b2(p2, p3, &pk.s[2]);
                *(uint2*)&Plds[buf][(16 * g + col) * PSTR + ms + 16 * mt + 4 * q] = pk.u;
            }
        }

        __syncthreads();   // P[buf] complete; P[buf^1] consumed last iter

        // ---- PV: O[c][n] += V[c][m] P[n][m]; va 1-deep prefetch ----
        v8s va_c[4];
        #pragma unroll
        for (int ct = 0; ct < 4; ct++)
            va_c[ct] = *(const v8s*)&Vb[(size_t)(((cslab + 16 * ct) >> 4) * 128 + (m0 >> 5)) * 512 + lane * 8];
        #pragma unroll
        for (int kk = 0; kk < 8; kk++){
            v8s va_n[4];
            if (kk < 7){
                #pragma unroll
                for (int ct = 0; ct < 4; ct++)
                    va_n[ct] = *(const v8s*)&Vb[(size_t)(((cslab + 16 * ct) >> 4) * 128 + (m0 >> 5) + kk + 1) * 512 + lane * 8];
            }
            v8s pb[4];
            #pragma unroll
            for (int nt = 0; nt < 4; nt++)
                pb[nt] = *(const v8s*)&Plds[buf][(16 * nt + col) * PSTR + 32 * kk + q * 8];
            #pragma unroll
            for (int ct = 0; ct < 4; ct++)
                #pragma unroll
                for (int nt = 0; nt < 4; nt++)
                    oacc[ct][nt] = mfma16(va_c[ct], pb[nt], oacc[ct][nt]);
            #pragma unroll
            for (int ct = 0; ct < 4; ct++) va_c[ct] = va_n[ct];
        }
    }

    // ---- finalize l: reduce over q, publish per wave, combine 4 m-strips ----
    #pragma unroll
    for (int g = 0; g < 4; g++){
        lreg[g] += __shfl_xor(lreg[g], 16);
        lreg[g] += __shfl_xor(lreg[g], 32);
    }
    if (lane < 16){
        #pragma unroll
        for (int g = 0; g < 4; g++)
            lsum[w][16 * g + lane] = lreg[g];
    }
    __syncthreads();

    const float gam = load_s(gamma, 0, isf32);
    float linv[4];
    #pragma unroll
    for (int nt = 0; nt < 4; nt++){
        int nn = 16 * nt + col;
        float l = lsum[0][nn] + lsum[1][nn] + lsum[2][nn] + lsum[3][nn];
        linv[nt] = gam / l;
    }

    // ---- epilogue: out = gamma*O/l + xbf ----
    const size_t boff = (size_t)b * CH * NPIX;
    #pragma unroll
    for (int ct = 0; ct < 4; ct++){
        #pragma unroll
        for (int rr = 0; rr < 4; rr++){
            int c = cslab + 16 * ct + 4 * q + rr;
            size_t base = boff + (size_t)c * NPIX + n0;
            #pragma unroll
            for (int nt = 0; nt < 4; nt++){
                int n = 16 * nt + col;
                float o = oacc[ct][nt][rr] * linv[nt] + b2f(xbf[base + n]);
                if (isf32) ((float*)out)[base + n] = o;
                else       ((u16*)out)[base + n]  = f2b(o);
            }
        }
    }
}

// ---------------------------------------------------------------------------
extern "C" void kernel_launch(void* const* d_in, const int* in_sizes, int n_in,
                              void* d_out, int out_size, void* d_ws, size_t ws_size,
                              hipStream_t stream)
{
    const void* x     = d_in[0];
    const void* wq    = d_in[1];
    const void* bq    = d_in[2];
    const void* wk    = d_in[3];
    const void* bk    = d_in[4];
    const void* wv    = d_in[5];
    const void* bv    = d_in[6];
    const void* gamma = d_in[7];

    u16* Qf   = (u16*)d_ws;                   // [B][N/16][2][512]
    u16* Kf   = Qf + (size_t)1048576;
    u16* Vf   = Kf + (size_t)1048576;         // [B][C/16][128][512]
    u16* xbf  = Vf + (size_t)8388608;         // [B][C][N] bf16
    u16* wall = xbf + (size_t)8388608;
    int* flag = (int*)(wall + WTOT + 16);

    detect_kernel<<<1, 64, 0, stream>>>((const unsigned*)x, flag);
    prep_kernel<<<(WTOT + 255) / 256, 256, 0, stream>>>(wq, bq, wk, bk, wv, bv, wall, flag);
    proj_kernel<<<dim3(64, 2, BATCH), 256, 0, stream>>>(x, wall, Qf, Kf, Vf, xbf, flag);
    attn_kernel<<<512, 256, 0, stream>>>(Qf, Kf, Vf, xbf, gamma, d_out, flag);
}